// Round 1
// baseline (5545.201 us; speedup 1.0000x reference)
//
#include <hip/hip_runtime.h>
#include <hip/hip_bf16.h>

#define BATCH 4096
#define DIM   512
#define HID   2048
#define NSTEPS 20

typedef __attribute__((ext_vector_type(8))) short short8;
typedef __attribute__((ext_vector_type(4))) float floatx4;

__device__ __forceinline__ short f2bf(float x) {
    union { float f; unsigned u; } v; v.f = x;
    unsigned r = v.u + 0x7fffu + ((v.u >> 16) & 1u);
    return (short)(r >> 16);
}

// dst[n][k] = bf16(src[k][n]); src is K x N row-major fp32
__global__ void transpose_cvt(const float* __restrict__ src, short* __restrict__ dst,
                              int K, int N) {
    __shared__ float tile[32][33];
    int k0 = blockIdx.x * 32, n0 = blockIdx.y * 32;
    int tx = threadIdx.x, ty = threadIdx.y;
    #pragma unroll
    for (int r = ty; r < 32; r += 8)
        tile[r][tx] = src[(size_t)(k0 + r) * N + n0 + tx];
    __syncthreads();
    #pragma unroll
    for (int r = ty; r < 32; r += 8)
        dst[(size_t)(n0 + r) * K + k0 + tx] = f2bf(tile[tx][r]);
}

__global__ void extract_row(const float* __restrict__ W1, float* __restrict__ w1last) {
    int i = blockIdx.x * 256 + threadIdx.x;
    w1last[i] = W1[(size_t)DIM * HID + i];
}

// hidden = tanh( (z + alpha*kprev) @ W1[:512] + b1 + t*W1[512,:] ), bf16 out
// A: computed on the fly (fp32->bf16). B: W1t bf16 [HID][DIM] (N x K).
__global__ __launch_bounds__(256, 2)
void gemm1_tanh(const float* __restrict__ z, const float* __restrict__ kprev,
                const short* __restrict__ Bt,
                const float* __restrict__ b1, const float* __restrict__ w1last,
                const float* __restrict__ t0p, const float* __restrict__ t1p,
                float c_alpha, float c_t, float step_i,
                short* __restrict__ hidden) {
    __shared__ short Alds[128 * 32];
    __shared__ short Blds[128 * 32];
    const int tid = threadIdx.x;
    const int lane = tid & 63;
    const int wave = tid >> 6;
    const int wm = wave >> 1, wn = wave & 1;
    const int bm0 = blockIdx.x * 128;   // 32 blocks over M
    const int bn0 = blockIdx.y * 128;   // 16 blocks over N

    const float t0 = t0p[0], t1 = t1p[0];
    const float h = (t1 - t0) / (float)NSTEPS;
    const float alpha = c_alpha * h;
    const float teval = t0 + (step_i + c_t) * h;

    floatx4 acc[4][4];
    #pragma unroll
    for (int i = 0; i < 4; i++)
        #pragma unroll
        for (int j = 0; j < 4; j++) acc[i][j] = (floatx4)0.f;

    for (int kk = 0; kk < DIM; kk += 32) {
        // async stage B tile [128][32] via global_load_lds (16B/lane)
        #pragma unroll
        for (int p = 0; p < 2; p++) {
            int c = tid + p * 256;
            int n = c >> 2, kc = (c & 3) * 8;
            const short* gp = Bt + (size_t)(bn0 + n) * DIM + kk + kc;
            __builtin_amdgcn_global_load_lds(
                (const __attribute__((address_space(1))) void*)gp,
                (__attribute__((address_space(3))) void*)&Blds[c * 8], 16, 0, 0);
        }
        // VALU stage A tile: bf16(z + alpha*kprev)
        #pragma unroll
        for (int p = 0; p < 2; p++) {
            int c = tid + p * 256;
            int row = c >> 2, kc = (c & 3) * 8;
            size_t off = (size_t)(bm0 + row) * DIM + kk + kc;
            float4 za = *(const float4*)(z + off);
            float4 zb = *(const float4*)(z + off + 4);
            float4 ka = *(const float4*)(kprev + off);
            float4 kb = *(const float4*)(kprev + off + 4);
            short8 pk;
            pk[0] = f2bf(za.x + alpha * ka.x);
            pk[1] = f2bf(za.y + alpha * ka.y);
            pk[2] = f2bf(za.z + alpha * ka.z);
            pk[3] = f2bf(za.w + alpha * ka.w);
            pk[4] = f2bf(zb.x + alpha * kb.x);
            pk[5] = f2bf(zb.y + alpha * kb.y);
            pk[6] = f2bf(zb.z + alpha * kb.z);
            pk[7] = f2bf(zb.w + alpha * kb.w);
            *(short8*)&Alds[c * 8] = pk;
        }
        __syncthreads();
        const int fr = lane & 15;
        const int fk = (lane >> 4) * 8;
        short8 af[4], bfr[4];
        #pragma unroll
        for (int mt = 0; mt < 4; mt++)
            af[mt] = *(const short8*)&Alds[(wm * 64 + mt * 16 + fr) * 32 + fk];
        #pragma unroll
        for (int nt = 0; nt < 4; nt++)
            bfr[nt] = *(const short8*)&Blds[(wn * 64 + nt * 16 + fr) * 32 + fk];
        #pragma unroll
        for (int mt = 0; mt < 4; mt++)
            #pragma unroll
            for (int nt = 0; nt < 4; nt++)
                acc[mt][nt] = __builtin_amdgcn_mfma_f32_16x16x32_bf16(af[mt], bfr[nt], acc[mt][nt], 0, 0, 0);
        __syncthreads();
    }
    // epilogue: + b1 + t*w1last, tanh, bf16 store
    #pragma unroll
    for (int nt = 0; nt < 4; nt++) {
        int col = bn0 + wn * 64 + nt * 16 + (lane & 15);
        float c1 = b1[col] + teval * w1last[col];
        #pragma unroll
        for (int mt = 0; mt < 4; mt++) {
            int row0 = bm0 + wm * 64 + mt * 16 + (lane >> 4) * 4;
            #pragma unroll
            for (int r = 0; r < 4; r++) {
                float v = acc[mt][nt][r] + c1;
                hidden[(size_t)(row0 + r) * HID + col] = f2bf(tanhf(v));
            }
        }
    }
}

// k = hidden @ W2 + b2 ; kout = k ; kacc = (mode==0) ? k : kacc + wk*k
__global__ __launch_bounds__(256, 2)
void gemm2_acc(const short* __restrict__ hidden,  // [BATCH][HID] bf16
               const short* __restrict__ Bt,      // W2t [DIM][HID] bf16
               const float* __restrict__ b2,
               float* __restrict__ kout, float* __restrict__ kacc,
               int mode, float wk) {
    __shared__ short Alds[128 * 32];
    __shared__ short Blds[64 * 32];
    const int tid = threadIdx.x;
    const int lane = tid & 63;
    const int wave = tid >> 6;
    const int wm = wave >> 1, wn = wave & 1;
    const int bm0 = blockIdx.x * 128;   // 32 blocks over M
    const int bn0 = blockIdx.y * 64;    // 8 blocks over N

    floatx4 acc[4][2];
    #pragma unroll
    for (int i = 0; i < 4; i++)
        #pragma unroll
        for (int j = 0; j < 2; j++) acc[i][j] = (floatx4)0.f;

    for (int kk = 0; kk < HID; kk += 32) {
        #pragma unroll
        for (int p = 0; p < 2; p++) {
            int c = tid + p * 256;
            int row = c >> 2, kc = (c & 3) * 8;
            const short* gp = hidden + (size_t)(bm0 + row) * HID + kk + kc;
            __builtin_amdgcn_global_load_lds(
                (const __attribute__((address_space(1))) void*)gp,
                (__attribute__((address_space(3))) void*)&Alds[c * 8], 16, 0, 0);
        }
        {
            int c = tid;
            int n = c >> 2, kc = (c & 3) * 8;
            const short* gp = Bt + (size_t)(bn0 + n) * HID + kk + kc;
            __builtin_amdgcn_global_load_lds(
                (const __attribute__((address_space(1))) void*)gp,
                (__attribute__((address_space(3))) void*)&Blds[c * 8], 16, 0, 0);
        }
        __syncthreads();
        const int fr = lane & 15;
        const int fk = (lane >> 4) * 8;
        short8 af[4], bfr[2];
        #pragma unroll
        for (int mt = 0; mt < 4; mt++)
            af[mt] = *(const short8*)&Alds[(wm * 64 + mt * 16 + fr) * 32 + fk];
        #pragma unroll
        for (int nt = 0; nt < 2; nt++)
            bfr[nt] = *(const short8*)&Blds[(wn * 32 + nt * 16 + fr) * 32 + fk];
        #pragma unroll
        for (int mt = 0; mt < 4; mt++)
            #pragma unroll
            for (int nt = 0; nt < 2; nt++)
                acc[mt][nt] = __builtin_amdgcn_mfma_f32_16x16x32_bf16(af[mt], bfr[nt], acc[mt][nt], 0, 0, 0);
        __syncthreads();
    }
    #pragma unroll
    for (int nt = 0; nt < 2; nt++) {
        int col = bn0 + wn * 32 + nt * 16 + (lane & 15);
        float bb = b2[col];
        #pragma unroll
        for (int mt = 0; mt < 4; mt++) {
            int row0 = bm0 + wm * 64 + mt * 16 + (lane >> 4) * 4;
            #pragma unroll
            for (int r = 0; r < 4; r++) {
                int row = row0 + r;
                float kv = acc[mt][nt][r] + bb;
                size_t idx = (size_t)row * DIM + col;
                kout[idx] = kv;
                kacc[idx] = (mode == 0) ? kv : (kacc[idx] + wk * kv);
            }
        }
    }
}

__global__ void update_z(float* __restrict__ z, const float* __restrict__ kacc,
                         const float* __restrict__ t0p, const float* __restrict__ t1p) {
    float h6 = (t1p[0] - t0p[0]) / (float)NSTEPS / 6.0f;
    size_t i = (size_t)(blockIdx.x * 256 + threadIdx.x) * 4;
    float4 zv = *(const float4*)(z + i);
    float4 kv = *(const float4*)(kacc + i);
    zv.x += h6 * kv.x;
    zv.y += h6 * kv.y;
    zv.z += h6 * kv.z;
    zv.w += h6 * kv.w;
    *(float4*)(z + i) = zv;
}

extern "C" void kernel_launch(void* const* d_in, const int* in_sizes, int n_in,
                              void* d_out, int out_size, void* d_ws, size_t ws_size,
                              hipStream_t stream) {
    const float* z0  = (const float*)d_in[0];
    const float* W1  = (const float*)d_in[1];
    const float* b1  = (const float*)d_in[2];
    const float* W2  = (const float*)d_in[3];
    const float* b2  = (const float*)d_in[4];
    const float* t0p = (const float*)d_in[5];
    const float* t1p = (const float*)d_in[6];
    float* z = (float*)d_out;

    char* ws = (char*)d_ws;
    short* W1t    = (short*)(ws);                                  // 2048*512 bf16 = 2MB
    short* W2t    = (short*)(ws + (2u << 20));                     // 512*2048 bf16 = 2MB
    float* w1last = (float*)(ws + (4u << 20));                     // 2048 f32 (pad to 64KB)
    short* hidden = (short*)(ws + (4u << 20) + (1u << 16));        // 4096*2048 bf16 = 16MB
    float* kbuf   = (float*)(ws + (20u << 20) + (1u << 16));       // 4096*512 f32 = 8MB
    float* kacc   = (float*)(ws + (28u << 20) + (1u << 16));       // 8MB

    hipMemcpyAsync(z, z0, (size_t)BATCH * DIM * sizeof(float),
                   hipMemcpyDeviceToDevice, stream);
    transpose_cvt<<<dim3(DIM / 32, HID / 32), dim3(32, 8), 0, stream>>>(W1, W1t, DIM, HID);
    transpose_cvt<<<dim3(HID / 32, DIM / 32), dim3(32, 8), 0, stream>>>(W2, W2t, HID, DIM);
    extract_row<<<HID / 256, 256, 0, stream>>>(W1, w1last);

    const dim3 g1(BATCH / 128, HID / 128), g2(BATCH / 128, DIM / 64), b(256);
    for (int i = 0; i < NSTEPS; i++) {
        float fi = (float)i;
        // k1
        gemm1_tanh<<<g1, b, 0, stream>>>(z, kbuf, W1t, b1, w1last, t0p, t1p, 0.0f, 0.0f, fi, hidden);
        gemm2_acc<<<g2, b, 0, stream>>>(hidden, W2t, b2, kbuf, kacc, 0, 1.0f);
        // k2
        gemm1_tanh<<<g1, b, 0, stream>>>(z, kbuf, W1t, b1, w1last, t0p, t1p, 0.5f, 0.5f, fi, hidden);
        gemm2_acc<<<g2, b, 0, stream>>>(hidden, W2t, b2, kbuf, kacc, 1, 2.0f);
        // k3
        gemm1_tanh<<<g1, b, 0, stream>>>(z, kbuf, W1t, b1, w1last, t0p, t1p, 0.5f, 0.5f, fi, hidden);
        gemm2_acc<<<g2, b, 0, stream>>>(hidden, W2t, b2, kbuf, kacc, 1, 2.0f);
        // k4
        gemm1_tanh<<<g1, b, 0, stream>>>(z, kbuf, W1t, b1, w1last, t0p, t1p, 1.0f, 1.0f, fi, hidden);
        gemm2_acc<<<g2, b, 0, stream>>>(hidden, W2t, b2, kbuf, kacc, 1, 1.0f);
        // z += (h/6) * kacc
        update_z<<<BATCH * DIM / 4 / 256, 256, 0, stream>>>(z, kacc, t0p, t1p);
    }
}

// Round 2
// 4430.094 us; speedup vs baseline: 1.2517x; 1.2517x over previous
//
#include <hip/hip_runtime.h>
#include <hip/hip_bf16.h>

#define BATCH 4096
#define DIM   512
#define HID   2048
#define NSTEPS 20

typedef __attribute__((ext_vector_type(8))) short short8;
typedef __attribute__((ext_vector_type(4))) short short4v;
typedef __attribute__((ext_vector_type(4))) float floatx4;

__device__ __forceinline__ short f2bf(float x) {
    union { float f; unsigned u; } v; v.f = x;
    unsigned r = v.u + 0x7fffu + ((v.u >> 16) & 1u);
    return (short)(r >> 16);
}

__device__ __forceinline__ float fast_tanh(float x) {
    float xx = fminf(fmaxf(x, -15.f), 15.f);
    float e = __expf(2.f * xx);
    return (e - 1.f) / (e + 1.f);
}

// dst[n][k] = bf16(src[k][n]); src is K x N row-major fp32
__global__ void transpose_cvt(const float* __restrict__ src, short* __restrict__ dst,
                              int K, int N) {
    __shared__ float tile[32][33];
    int k0 = blockIdx.x * 32, n0 = blockIdx.y * 32;
    int tx = threadIdx.x, ty = threadIdx.y;
    #pragma unroll
    for (int r = ty; r < 32; r += 8)
        tile[r][tx] = src[(size_t)(k0 + r) * N + n0 + tx];
    __syncthreads();
    #pragma unroll
    for (int r = ty; r < 32; r += 8)
        dst[(size_t)(n0 + r) * K + k0 + tx] = f2bf(tile[tx][r]);
}

__global__ void extract_row(const float* __restrict__ W1, float* __restrict__ w1last) {
    int i = blockIdx.x * 256 + threadIdx.x;
    w1last[i] = W1[(size_t)DIM * HID + i];
}

__global__ void init_abuf(const float* __restrict__ z0, short* __restrict__ abuf) {
    size_t i = (size_t)(blockIdx.x * 256 + threadIdx.x) * 4;
    float4 zv = *(const float4*)(z0 + i);
    short4v o;
    o[0] = f2bf(zv.x); o[1] = f2bf(zv.y); o[2] = f2bf(zv.z); o[3] = f2bf(zv.w);
    *(short4v*)(abuf + i) = o;
}

// hidden = tanh( A @ W1[:512]^T(row) + b1 + t*w1last ), bf16 out
// A: abuf bf16 [BATCH][DIM].  B: W1t bf16 [HID][DIM] (N x K).
__global__ __launch_bounds__(256, 2)
void gemm1_tanh(const short* __restrict__ A, const short* __restrict__ Bt,
                const float* __restrict__ b1, const float* __restrict__ w1last,
                const float* __restrict__ t0p, const float* __restrict__ t1p,
                float c_t, float step_i,
                short* __restrict__ hidden) {
    __shared__ short Alds[128 * 32];
    __shared__ short Blds[128 * 32];
    const int tid = threadIdx.x;
    const int lane = tid & 63;
    const int wave = tid >> 6;
    const int wm = wave >> 1, wn = wave & 1;
    const int bm0 = blockIdx.x * 128;   // 32 blocks over M
    const int bn0 = blockIdx.y * 128;   // 16 blocks over N

    const float t0 = t0p[0], t1 = t1p[0];
    const float h = (t1 - t0) / (float)NSTEPS;
    const float teval = t0 + (step_i + c_t) * h;

    floatx4 acc[4][4];
    #pragma unroll
    for (int i = 0; i < 4; i++)
        #pragma unroll
        for (int j = 0; j < 4; j++) acc[i][j] = (floatx4)0.f;

    for (int kk = 0; kk < DIM; kk += 32) {
        #pragma unroll
        for (int p = 0; p < 2; p++) {
            int c = tid + p * 256;
            int row = c >> 2, kc = (c & 3) * 8;
            const short* gpA = A + (size_t)(bm0 + row) * DIM + kk + kc;
            __builtin_amdgcn_global_load_lds(
                (const __attribute__((address_space(1))) void*)gpA,
                (__attribute__((address_space(3))) void*)&Alds[c * 8], 16, 0, 0);
            const short* gpB = Bt + (size_t)(bn0 + row) * DIM + kk + kc;
            __builtin_amdgcn_global_load_lds(
                (const __attribute__((address_space(1))) void*)gpB,
                (__attribute__((address_space(3))) void*)&Blds[c * 8], 16, 0, 0);
        }
        __syncthreads();
        const int fr = lane & 15;
        const int fk = (lane >> 4) * 8;
        short8 af[4], bfr[4];
        #pragma unroll
        for (int mt = 0; mt < 4; mt++)
            af[mt] = *(const short8*)&Alds[(wm * 64 + mt * 16 + fr) * 32 + fk];
        #pragma unroll
        for (int nt = 0; nt < 4; nt++)
            bfr[nt] = *(const short8*)&Blds[(wn * 64 + nt * 16 + fr) * 32 + fk];
        #pragma unroll
        for (int mt = 0; mt < 4; mt++)
            #pragma unroll
            for (int nt = 0; nt < 4; nt++)
                acc[mt][nt] = __builtin_amdgcn_mfma_f32_16x16x32_bf16(af[mt], bfr[nt], acc[mt][nt], 0, 0, 0);
        __syncthreads();
    }
    // epilogue: + b1 + t*w1last, tanh, bf16 store
    #pragma unroll
    for (int nt = 0; nt < 4; nt++) {
        int col = bn0 + wn * 64 + nt * 16 + (lane & 15);
        float c1 = b1[col] + teval * w1last[col];
        #pragma unroll
        for (int mt = 0; mt < 4; mt++) {
            int row0 = bm0 + wm * 64 + mt * 16 + (lane >> 4) * 4;
            #pragma unroll
            for (int r = 0; r < 4; r++) {
                float v = acc[mt][nt][r] + c1;
                hidden[(size_t)(row0 + r) * HID + col] = f2bf(fast_tanh(v));
            }
        }
    }
}

// k = hidden @ W2 + b2
// kacc = (mode==0) ? k : kacc + wk*k
// if alpha_c >= 0: abuf = bf16(z + alpha_c*h*k)   (A-matrix for next RK stage)
__global__ __launch_bounds__(256, 4)
void gemm2_fused(const short* __restrict__ hidden,  // [BATCH][HID] bf16
                 const short* __restrict__ Bt,      // W2t [DIM][HID] bf16
                 const float* __restrict__ b2,
                 const float* __restrict__ z,
                 float* __restrict__ kacc, short* __restrict__ abuf,
                 const float* __restrict__ t0p, const float* __restrict__ t1p,
                 int mode, float wk, float alpha_c) {
    __shared__ short Alds[64 * 64];   // 8 KB
    __shared__ short Blds[64 * 64];   // 8 KB
    const int tid = threadIdx.x;
    const int lane = tid & 63;
    const int wave = tid >> 6;
    const int wm = wave >> 1, wn = wave & 1;
    const int bm0 = blockIdx.x * 64;   // 64 blocks over M
    const int bn0 = blockIdx.y * 64;   // 8 blocks over N

    floatx4 acc[2][2];
    #pragma unroll
    for (int i = 0; i < 2; i++)
        #pragma unroll
        for (int j = 0; j < 2; j++) acc[i][j] = (floatx4)0.f;

    for (int kk = 0; kk < HID; kk += 64) {
        #pragma unroll
        for (int p = 0; p < 2; p++) {
            int c = tid + p * 256;
            int row = c >> 3, kc = (c & 7) * 8;
            const short* gpA = hidden + (size_t)(bm0 + row) * HID + kk + kc;
            __builtin_amdgcn_global_load_lds(
                (const __attribute__((address_space(1))) void*)gpA,
                (__attribute__((address_space(3))) void*)&Alds[c * 8], 16, 0, 0);
            const short* gpB = Bt + (size_t)(bn0 + row) * HID + kk + kc;
            __builtin_amdgcn_global_load_lds(
                (const __attribute__((address_space(1))) void*)gpB,
                (__attribute__((address_space(3))) void*)&Blds[c * 8], 16, 0, 0);
        }
        __syncthreads();
        const int fr = lane & 15;
        const int fk = (lane >> 4) * 8;
        #pragma unroll
        for (int s = 0; s < 2; s++) {
            short8 af[2], bfr[2];
            #pragma unroll
            for (int mt = 0; mt < 2; mt++)
                af[mt] = *(const short8*)&Alds[(wm * 32 + mt * 16 + fr) * 64 + s * 32 + fk];
            #pragma unroll
            for (int nt = 0; nt < 2; nt++)
                bfr[nt] = *(const short8*)&Blds[(wn * 32 + nt * 16 + fr) * 64 + s * 32 + fk];
            #pragma unroll
            for (int mt = 0; mt < 2; mt++)
                #pragma unroll
                for (int nt = 0; nt < 2; nt++)
                    acc[mt][nt] = __builtin_amdgcn_mfma_f32_16x16x32_bf16(af[mt], bfr[nt], acc[mt][nt], 0, 0, 0);
        }
        __syncthreads();
    }

    const float h = (t1p[0] - t0p[0]) / (float)NSTEPS;
    const float alpha = (alpha_c >= 0.f ? alpha_c : 0.f) * h;
    #pragma unroll
    for (int nt = 0; nt < 2; nt++) {
        int col = bn0 + wn * 32 + nt * 16 + (lane & 15);
        float bb = b2[col];
        #pragma unroll
        for (int mt = 0; mt < 2; mt++) {
            int row0 = bm0 + wm * 32 + mt * 16 + (lane >> 4) * 4;
            #pragma unroll
            for (int r = 0; r < 4; r++) {
                int row = row0 + r;
                float kv = acc[mt][nt][r] + bb;
                size_t idx = (size_t)row * DIM + col;
                kacc[idx] = (mode == 0) ? kv : (kacc[idx] + wk * kv);
                if (alpha_c >= 0.f)
                    abuf[idx] = f2bf(z[idx] + alpha * kv);
            }
        }
    }
}

// z += (h/6)*kacc ; abuf = bf16(z_new)  (A-matrix for next step's k1)
__global__ void update_z(float* __restrict__ z, const float* __restrict__ kacc,
                         short* __restrict__ abuf,
                         const float* __restrict__ t0p, const float* __restrict__ t1p) {
    float h6 = (t1p[0] - t0p[0]) / (float)NSTEPS / 6.0f;
    size_t i = (size_t)(blockIdx.x * 256 + threadIdx.x) * 4;
    float4 zv = *(const float4*)(z + i);
    float4 kv = *(const float4*)(kacc + i);
    zv.x += h6 * kv.x;
    zv.y += h6 * kv.y;
    zv.z += h6 * kv.z;
    zv.w += h6 * kv.w;
    *(float4*)(z + i) = zv;
    short4v o;
    o[0] = f2bf(zv.x); o[1] = f2bf(zv.y); o[2] = f2bf(zv.z); o[3] = f2bf(zv.w);
    *(short4v*)(abuf + i) = o;
}

extern "C" void kernel_launch(void* const* d_in, const int* in_sizes, int n_in,
                              void* d_out, int out_size, void* d_ws, size_t ws_size,
                              hipStream_t stream) {
    const float* z0  = (const float*)d_in[0];
    const float* W1  = (const float*)d_in[1];
    const float* b1  = (const float*)d_in[2];
    const float* W2  = (const float*)d_in[3];
    const float* b2  = (const float*)d_in[4];
    const float* t0p = (const float*)d_in[5];
    const float* t1p = (const float*)d_in[6];
    float* z = (float*)d_out;

    char* ws = (char*)d_ws;
    short* W1t    = (short*)(ws);                              // 2 MB
    short* W2t    = (short*)(ws + (2u << 20));                 // 2 MB
    float* w1last = (float*)(ws + (4u << 20));                 // 8 KB (pad 64 KB)
    short* abuf   = (short*)(ws + (4u << 20) + (1u << 16));    // 4 MB
    short* hidden = (short*)(ws + (8u << 20) + (1u << 16));    // 16 MB
    float* kacc   = (float*)(ws + (24u << 20) + (1u << 16));   // 8 MB

    hipMemcpyAsync(z, z0, (size_t)BATCH * DIM * sizeof(float),
                   hipMemcpyDeviceToDevice, stream);
    transpose_cvt<<<dim3(DIM / 32, HID / 32), dim3(32, 8), 0, stream>>>(W1, W1t, DIM, HID);
    transpose_cvt<<<dim3(HID / 32, DIM / 32), dim3(32, 8), 0, stream>>>(W2, W2t, HID, DIM);
    extract_row<<<HID / 256, 256, 0, stream>>>(W1, w1last);
    init_abuf<<<BATCH * DIM / 4 / 256, 256, 0, stream>>>(z0, abuf);

    const dim3 g1(BATCH / 128, HID / 128), g2(BATCH / 64, DIM / 64), b(256);
    for (int i = 0; i < NSTEPS; i++) {
        float fi = (float)i;
        // k1 -> abuf for k2
        gemm1_tanh<<<g1, b, 0, stream>>>(abuf, W1t, b1, w1last, t0p, t1p, 0.0f, fi, hidden);
        gemm2_fused<<<g2, b, 0, stream>>>(hidden, W2t, b2, z, kacc, abuf, t0p, t1p, 0, 1.0f, 0.5f);
        // k2 -> abuf for k3
        gemm1_tanh<<<g1, b, 0, stream>>>(abuf, W1t, b1, w1last, t0p, t1p, 0.5f, fi, hidden);
        gemm2_fused<<<g2, b, 0, stream>>>(hidden, W2t, b2, z, kacc, abuf, t0p, t1p, 1, 2.0f, 0.5f);
        // k3 -> abuf for k4
        gemm1_tanh<<<g1, b, 0, stream>>>(abuf, W1t, b1, w1last, t0p, t1p, 0.5f, fi, hidden);
        gemm2_fused<<<g2, b, 0, stream>>>(hidden, W2t, b2, z, kacc, abuf, t0p, t1p, 1, 2.0f, 1.0f);
        // k4 (no abuf)
        gemm1_tanh<<<g1, b, 0, stream>>>(abuf, W1t, b1, w1last, t0p, t1p, 1.0f, fi, hidden);
        gemm2_fused<<<g2, b, 0, stream>>>(hidden, W2t, b2, z, kacc, abuf, t0p, t1p, 1, 1.0f, -1.0f);
        // z += (h/6)*kacc ; abuf = bf16(z) for next step
        update_z<<<BATCH * DIM / 4 / 256, 256, 0, stream>>>(z, kacc, abuf, t0p, t1p);
    }
}

// Round 3
// 3747.946 us; speedup vs baseline: 1.4795x; 1.1820x over previous
//
#include <hip/hip_runtime.h>
#include <hip/hip_bf16.h>

#define BATCH 4096
#define DIM   512
#define HID   2048
#define NSTEPS 20

typedef __attribute__((ext_vector_type(8))) short short8;
typedef __attribute__((ext_vector_type(4))) short short4v;
typedef __attribute__((ext_vector_type(4))) float floatx4;

__device__ __forceinline__ short f2bf(float x) {
    union { float f; unsigned u; } v; v.f = x;
    unsigned r = v.u + 0x7fffu + ((v.u >> 16) & 1u);
    return (short)(r >> 16);
}

// tanh(x) = 1 - 2/(1 + e^{2x}) = 1 - 2*rcp(1 + exp2(2*log2e * x))
// Saturates correctly: x->+inf: rcp(inf)=0 -> 1 ; x->-inf: rcp(1)=1 -> -1.
__device__ __forceinline__ float fast_tanh(float x) {
    float e = __builtin_amdgcn_exp2f(x * 2.8853900817779268f);
    float r = __builtin_amdgcn_rcpf(1.0f + e);
    return 1.0f - 2.0f * r;
}

// dst[n][k] = bf16(src[k][n]); src is K x N row-major fp32
__global__ void transpose_cvt(const float* __restrict__ src, short* __restrict__ dst,
                              int K, int N) {
    __shared__ float tile[32][33];
    int k0 = blockIdx.x * 32, n0 = blockIdx.y * 32;
    int tx = threadIdx.x, ty = threadIdx.y;
    #pragma unroll
    for (int r = ty; r < 32; r += 8)
        tile[r][tx] = src[(size_t)(k0 + r) * N + n0 + tx];
    __syncthreads();
    #pragma unroll
    for (int r = ty; r < 32; r += 8)
        dst[(size_t)(n0 + r) * K + k0 + tx] = f2bf(tile[tx][r]);
}

__global__ void extract_row(const float* __restrict__ W1, float* __restrict__ w1last) {
    int i = blockIdx.x * 256 + threadIdx.x;
    w1last[i] = W1[(size_t)DIM * HID + i];
}

__global__ void init_abuf(const float* __restrict__ z0, short* __restrict__ abuf) {
    size_t i = (size_t)(blockIdx.x * 256 + threadIdx.x) * 4;
    float4 zv = *(const float4*)(z0 + i);
    short4v o;
    o[0] = f2bf(zv.x); o[1] = f2bf(zv.y); o[2] = f2bf(zv.z); o[3] = f2bf(zv.w);
    *(short4v*)(abuf + i) = o;
}

// hidden = tanh( A @ W1t^T + b1 + t*w1last ), bf16 out
// A: abuf bf16 [BATCH][DIM].  B: W1t bf16 [HID][DIM] (N x K).  BK=64.
__global__ __launch_bounds__(256, 2)
void gemm1_tanh(const short* __restrict__ A, const short* __restrict__ Bt,
                const float* __restrict__ b1, const float* __restrict__ w1last,
                const float* __restrict__ t0p, const float* __restrict__ t1p,
                float c_t, float step_i,
                short* __restrict__ hidden) {
    __shared__ short Alds[128 * 64];   // 16 KB
    __shared__ short Blds[128 * 64];   // 16 KB
    const int tid = threadIdx.x;
    const int lane = tid & 63;
    const int wave = tid >> 6;
    const int wm = wave >> 1, wn = wave & 1;
    const int bm0 = blockIdx.x * 128;   // 32 blocks over M
    const int bn0 = blockIdx.y * 128;   // 16 blocks over N

    const float t0 = t0p[0], t1 = t1p[0];
    const float h = (t1 - t0) / (float)NSTEPS;
    const float teval = t0 + (step_i + c_t) * h;

    floatx4 acc[4][4];
    #pragma unroll
    for (int i = 0; i < 4; i++)
        #pragma unroll
        for (int j = 0; j < 4; j++) acc[i][j] = (floatx4)0.f;

    for (int kk = 0; kk < DIM; kk += 64) {
        #pragma unroll
        for (int p = 0; p < 4; p++) {
            int c = tid + p * 256;
            int row = c >> 3, kc = (c & 7) * 8;   // 8 chunks of 16B per 64-col row
            const short* gpA = A + (size_t)(bm0 + row) * DIM + kk + kc;
            __builtin_amdgcn_global_load_lds(
                (const __attribute__((address_space(1))) void*)gpA,
                (__attribute__((address_space(3))) void*)&Alds[c * 8], 16, 0, 0);
            const short* gpB = Bt + (size_t)(bn0 + row) * DIM + kk + kc;
            __builtin_amdgcn_global_load_lds(
                (const __attribute__((address_space(1))) void*)gpB,
                (__attribute__((address_space(3))) void*)&Blds[c * 8], 16, 0, 0);
        }
        __syncthreads();
        const int fr = lane & 15;
        const int fk = (lane >> 4) * 8;
        #pragma unroll
        for (int s = 0; s < 2; s++) {
            short8 af[4], bfr[4];
            #pragma unroll
            for (int mt = 0; mt < 4; mt++)
                af[mt] = *(const short8*)&Alds[(wm * 64 + mt * 16 + fr) * 64 + s * 32 + fk];
            #pragma unroll
            for (int nt = 0; nt < 4; nt++)
                bfr[nt] = *(const short8*)&Blds[(wn * 64 + nt * 16 + fr) * 64 + s * 32 + fk];
            #pragma unroll
            for (int mt = 0; mt < 4; mt++)
                #pragma unroll
                for (int nt = 0; nt < 4; nt++)
                    acc[mt][nt] = __builtin_amdgcn_mfma_f32_16x16x32_bf16(af[mt], bfr[nt], acc[mt][nt], 0, 0, 0);
        }
        __syncthreads();
    }
    // epilogue: + b1 + t*w1last, tanh, bf16 store
    #pragma unroll
    for (int nt = 0; nt < 4; nt++) {
        int col = bn0 + wn * 64 + nt * 16 + (lane & 15);
        float c1 = b1[col] + teval * w1last[col];
        #pragma unroll
        for (int mt = 0; mt < 4; mt++) {
            int row0 = bm0 + wm * 64 + mt * 16 + (lane >> 4) * 4;
            #pragma unroll
            for (int r = 0; r < 4; r++) {
                float v = acc[mt][nt][r] + c1;
                hidden[(size_t)(row0 + r) * HID + col] = f2bf(fast_tanh(v));
            }
        }
    }
}

// k = hidden @ W2 + b2     (32x64 tile, BK=64, 1024 blocks = 4/CU)
// mode 0 (k1): kacc = k;            abuf = bf16(z + alpha*h*k)
// mode 1 (k2/k3): kacc += wk*k;     abuf = bf16(z + alpha*h*k)
// mode 2 (k4): z += (h/6)*(kacc+k); abuf = bf16(z_new)
__global__ __launch_bounds__(256, 4)
void gemm2_fused(const short* __restrict__ hidden,  // [BATCH][HID] bf16
                 const short* __restrict__ Bt,      // W2t [DIM][HID] bf16
                 const float* __restrict__ b2,
                 float* __restrict__ z,
                 float* __restrict__ kacc, short* __restrict__ abuf,
                 const float* __restrict__ t0p, const float* __restrict__ t1p,
                 int mode, float wk, float alpha_c) {
    __shared__ short Alds[32 * 64];   // 4 KB
    __shared__ short Blds[64 * 64];   // 8 KB
    const int tid = threadIdx.x;
    const int lane = tid & 63;
    const int wave = tid >> 6;
    const int wm = wave >> 1, wn = wave & 1;
    const int bm0 = blockIdx.x * 32;   // 128 blocks over M
    const int bn0 = blockIdx.y * 64;   // 8 blocks over N

    floatx4 acc[2];
    acc[0] = (floatx4)0.f; acc[1] = (floatx4)0.f;

    for (int kk = 0; kk < HID; kk += 64) {
        {   // A tile 32x64 : 256 chunks, 1 per thread
            int row = tid >> 3, kc = (tid & 7) * 8;
            const short* gpA = hidden + (size_t)(bm0 + row) * HID + kk + kc;
            __builtin_amdgcn_global_load_lds(
                (const __attribute__((address_space(1))) void*)gpA,
                (__attribute__((address_space(3))) void*)&Alds[tid * 8], 16, 0, 0);
        }
        #pragma unroll
        for (int p = 0; p < 2; p++) {   // B tile 64x64 : 512 chunks
            int c = tid + p * 256;
            int row = c >> 3, kc = (c & 7) * 8;
            const short* gpB = Bt + (size_t)(bn0 + row) * HID + kk + kc;
            __builtin_amdgcn_global_load_lds(
                (const __attribute__((address_space(1))) void*)gpB,
                (__attribute__((address_space(3))) void*)&Blds[c * 8], 16, 0, 0);
        }
        __syncthreads();
        const int fr = lane & 15;
        const int fk = (lane >> 4) * 8;
        #pragma unroll
        for (int s = 0; s < 2; s++) {
            short8 af = *(const short8*)&Alds[(wm * 16 + fr) * 64 + s * 32 + fk];
            #pragma unroll
            for (int nt = 0; nt < 2; nt++) {
                short8 bfr = *(const short8*)&Blds[(wn * 32 + nt * 16 + fr) * 64 + s * 32 + fk];
                acc[nt] = __builtin_amdgcn_mfma_f32_16x16x32_bf16(af, bfr, acc[nt], 0, 0, 0);
            }
        }
        __syncthreads();
    }

    const float h = (t1p[0] - t0p[0]) / (float)NSTEPS;
    const float ah = alpha_c * h;
    const float h6 = h / 6.0f;
    #pragma unroll
    for (int nt = 0; nt < 2; nt++) {
        int col = bn0 + wn * 32 + nt * 16 + (lane & 15);
        float bb = b2[col];
        int row0 = bm0 + wm * 16 + (lane >> 4) * 4;
        #pragma unroll
        for (int r = 0; r < 4; r++) {
            int row = row0 + r;
            float kv = acc[nt][r] + bb;
            size_t idx = (size_t)row * DIM + col;
            if (mode == 0) {
                kacc[idx] = kv;
                abuf[idx] = f2bf(z[idx] + ah * kv);
            } else if (mode == 1) {
                kacc[idx] += wk * kv;
                abuf[idx] = f2bf(z[idx] + ah * kv);
            } else {
                float zn = z[idx] + h6 * (kacc[idx] + kv);
                z[idx] = zn;
                abuf[idx] = f2bf(zn);
            }
        }
    }
}

extern "C" void kernel_launch(void* const* d_in, const int* in_sizes, int n_in,
                              void* d_out, int out_size, void* d_ws, size_t ws_size,
                              hipStream_t stream) {
    const float* z0  = (const float*)d_in[0];
    const float* W1  = (const float*)d_in[1];
    const float* b1  = (const float*)d_in[2];
    const float* W2  = (const float*)d_in[3];
    const float* b2  = (const float*)d_in[4];
    const float* t0p = (const float*)d_in[5];
    const float* t1p = (const float*)d_in[6];
    float* z = (float*)d_out;

    char* ws = (char*)d_ws;
    short* W1t    = (short*)(ws);                              // 2 MB
    short* W2t    = (short*)(ws + (2u << 20));                 // 2 MB
    float* w1last = (float*)(ws + (4u << 20));                 // 8 KB (pad 64 KB)
    short* abuf   = (short*)(ws + (4u << 20) + (1u << 16));    // 4 MB
    short* hidden = (short*)(ws + (8u << 20) + (1u << 16));    // 16 MB
    float* kacc   = (float*)(ws + (24u << 20) + (1u << 16));   // 8 MB

    hipMemcpyAsync(z, z0, (size_t)BATCH * DIM * sizeof(float),
                   hipMemcpyDeviceToDevice, stream);
    transpose_cvt<<<dim3(DIM / 32, HID / 32), dim3(32, 8), 0, stream>>>(W1, W1t, DIM, HID);
    transpose_cvt<<<dim3(HID / 32, DIM / 32), dim3(32, 8), 0, stream>>>(W2, W2t, HID, DIM);
    extract_row<<<HID / 256, 256, 0, stream>>>(W1, w1last);
    init_abuf<<<BATCH * DIM / 4 / 256, 256, 0, stream>>>(z0, abuf);

    const dim3 g1(BATCH / 128, HID / 128), g2(BATCH / 32, DIM / 64), b(256);
    for (int i = 0; i < NSTEPS; i++) {
        float fi = (float)i;
        // k1 -> abuf for k2
        gemm1_tanh<<<g1, b, 0, stream>>>(abuf, W1t, b1, w1last, t0p, t1p, 0.0f, fi, hidden);
        gemm2_fused<<<g2, b, 0, stream>>>(hidden, W2t, b2, z, kacc, abuf, t0p, t1p, 0, 1.0f, 0.5f);
        // k2 -> abuf for k3
        gemm1_tanh<<<g1, b, 0, stream>>>(abuf, W1t, b1, w1last, t0p, t1p, 0.5f, fi, hidden);
        gemm2_fused<<<g2, b, 0, stream>>>(hidden, W2t, b2, z, kacc, abuf, t0p, t1p, 1, 2.0f, 0.5f);
        // k3 -> abuf for k4
        gemm1_tanh<<<g1, b, 0, stream>>>(abuf, W1t, b1, w1last, t0p, t1p, 0.5f, fi, hidden);
        gemm2_fused<<<g2, b, 0, stream>>>(hidden, W2t, b2, z, kacc, abuf, t0p, t1p, 1, 2.0f, 1.0f);
        // k4: z += (h/6)*(kacc + k4) ; abuf = bf16(z_new)
        gemm1_tanh<<<g1, b, 0, stream>>>(abuf, W1t, b1, w1last, t0p, t1p, 1.0f, fi, hidden);
        gemm2_fused<<<g2, b, 0, stream>>>(hidden, W2t, b2, z, kacc, abuf, t0p, t1p, 2, 1.0f, 0.0f);
    }
}

// Round 4
// 3099.577 us; speedup vs baseline: 1.7890x; 1.2092x over previous
//
#include <hip/hip_runtime.h>
#include <hip/hip_bf16.h>

#define BATCH 4096
#define DIM   512
#define HID   2048
#define NSTEPS 20

typedef __attribute__((ext_vector_type(8))) short short8;
typedef __attribute__((ext_vector_type(4))) short short4v;
typedef __attribute__((ext_vector_type(4))) float floatx4;

__device__ __forceinline__ short f2bf(float x) {
    union { float f; unsigned u; } v; v.f = x;
    unsigned r = v.u + 0x7fffu + ((v.u >> 16) & 1u);
    return (short)(r >> 16);
}

// tanh(x) = 1 - 2*rcp(1 + exp2(2*log2e*x)); saturates correctly at +-inf
__device__ __forceinline__ float fast_tanh(float x) {
    float e = __builtin_amdgcn_exp2f(x * 2.8853900817779268f);
    float r = __builtin_amdgcn_rcpf(1.0f + e);
    return 1.0f - 2.0f * r;
}

// dst[n][k] = bf16(src[k][n]); src is K x N row-major fp32
__global__ void transpose_cvt(const float* __restrict__ src, short* __restrict__ dst,
                              int K, int N) {
    __shared__ float tile[32][33];
    int k0 = blockIdx.x * 32, n0 = blockIdx.y * 32;
    int tx = threadIdx.x, ty = threadIdx.y;
    #pragma unroll
    for (int r = ty; r < 32; r += 8)
        tile[r][tx] = src[(size_t)(k0 + r) * N + n0 + tx];
    __syncthreads();
    #pragma unroll
    for (int r = ty; r < 32; r += 8)
        dst[(size_t)(n0 + r) * K + k0 + tx] = f2bf(tile[tx][r]);
}

__global__ void extract_row(const float* __restrict__ W1, float* __restrict__ w1last) {
    int i = blockIdx.x * 256 + threadIdx.x;
    w1last[i] = W1[(size_t)DIM * HID + i];
}

__global__ void init_abuf(const float* __restrict__ z0, short* __restrict__ abuf) {
    size_t i = (size_t)(blockIdx.x * 256 + threadIdx.x) * 4;
    float4 zv = *(const float4*)(z0 + i);
    short4v o;
    o[0] = f2bf(zv.x); o[1] = f2bf(zv.y); o[2] = f2bf(zv.z); o[3] = f2bf(zv.w);
    *(short4v*)(abuf + i) = o;
}

// hidden = tanh( A @ W1t^T + b1 + t*w1last ), bf16 out.
// 128x128 tile, BK=64, XOR-swizzled LDS (global-side swizzle, conflict-free frag reads).
__global__ __launch_bounds__(256, 2)
void gemm1_tanh(const short* __restrict__ A, const short* __restrict__ Bt,
                const float* __restrict__ b1, const float* __restrict__ w1last,
                const float* __restrict__ t0p, const float* __restrict__ t1p,
                float c_t, float step_i,
                short* __restrict__ hidden) {
    __shared__ short Alds[128 * 64];   // 16 KB
    __shared__ short Blds[128 * 64];   // 16 KB
    const int tid = threadIdx.x;
    const int lane = tid & 63;
    const int wave = tid >> 6;
    const int wm = wave >> 1, wn = wave & 1;
    const int bm0 = blockIdx.x * 128;
    const int bn0 = blockIdx.y * 128;

    const float t0 = t0p[0], t1 = t1p[0];
    const float h = (t1 - t0) / (float)NSTEPS;
    const float teval = t0 + (step_i + c_t) * h;

    floatx4 acc[4][4];
    #pragma unroll
    for (int i = 0; i < 4; i++)
        #pragma unroll
        for (int j = 0; j < 4; j++) acc[i][j] = (floatx4)0.f;

    const int fr = lane & 15;
    const int fkc = lane >> 4;     // 0..3
    const int rx = fr & 7;

    for (int kk = 0; kk < DIM; kk += 64) {
        #pragma unroll
        for (int p = 0; p < 4; p++) {
            int c = tid + p * 256;
            int row = c >> 3;
            int g = (c & 7) ^ (row & 7);   // swizzled global k-chunk
            const short* gpA = A + (size_t)(bm0 + row) * DIM + kk + g * 8;
            __builtin_amdgcn_global_load_lds(
                (const __attribute__((address_space(1))) void*)gpA,
                (__attribute__((address_space(3))) void*)&Alds[c * 8], 16, 0, 0);
            const short* gpB = Bt + (size_t)(bn0 + row) * DIM + kk + g * 8;
            __builtin_amdgcn_global_load_lds(
                (const __attribute__((address_space(1))) void*)gpB,
                (__attribute__((address_space(3))) void*)&Blds[c * 8], 16, 0, 0);
        }
        __syncthreads();
        #pragma unroll
        for (int s = 0; s < 2; s++) {
            const int slot = ((s * 4 + fkc) ^ rx) * 8;
            short8 af[4], bfr[4];
            #pragma unroll
            for (int mt = 0; mt < 4; mt++)
                af[mt] = *(const short8*)&Alds[(wm * 64 + mt * 16 + fr) * 64 + slot];
            #pragma unroll
            for (int nt = 0; nt < 4; nt++)
                bfr[nt] = *(const short8*)&Blds[(wn * 64 + nt * 16 + fr) * 64 + slot];
            #pragma unroll
            for (int mt = 0; mt < 4; mt++)
                #pragma unroll
                for (int nt = 0; nt < 4; nt++)
                    acc[mt][nt] = __builtin_amdgcn_mfma_f32_16x16x32_bf16(af[mt], bfr[nt], acc[mt][nt], 0, 0, 0);
        }
        __syncthreads();
    }
    #pragma unroll
    for (int nt = 0; nt < 4; nt++) {
        int col = bn0 + wn * 64 + nt * 16 + fr;
        float c1 = b1[col] + teval * w1last[col];
        #pragma unroll
        for (int mt = 0; mt < 4; mt++) {
            int row0 = bm0 + wm * 64 + mt * 16 + fkc * 4;
            #pragma unroll
            for (int r = 0; r < 4; r++) {
                float v = acc[mt][nt][r] + c1;
                hidden[(size_t)(row0 + r) * HID + col] = f2bf(fast_tanh(v));
            }
        }
    }
}

// k = hidden @ W2t^T + b2.  64x64 tile, 4-way K-split across waves (wave-tile 64x64
// over K=512), per-wave private LDS slab, NO barriers in K-loop (per-wave vmcnt only).
// mode 0 (k1): kacc = k;            abuf = bf16(z + alpha*h*k)
// mode 1 (k2/k3): kacc += wk*k;     abuf = bf16(z + alpha*h*k)
// mode 2 (k4): z += (h/6)*(kacc+k); abuf = bf16(z_new)
__global__ __launch_bounds__(256, 2)
void gemm2_fused(const short* __restrict__ hidden,  // [BATCH][HID] bf16
                 const short* __restrict__ Bt,      // W2t [DIM][HID] bf16
                 const float* __restrict__ b2,
                 float* __restrict__ z,
                 float* __restrict__ kacc, short* __restrict__ abuf,
                 const float* __restrict__ t0p, const float* __restrict__ t1p,
                 int mode, float wk, float alpha_c) {
    __shared__ short lds[4 * 8192];    // 4 slabs x 16 KB (A[64][64] + B[64][64])
    const int tid = threadIdx.x;
    const int lane = tid & 63;
    const int wave = tid >> 6;          // K-split index
    const int bm0 = blockIdx.x * 64;    // 64 blocks over M
    const int bn0 = blockIdx.y * 64;    // 8 blocks over N
    const int kbase = wave * 512;

    short* slabA = &lds[wave * 8192];
    short* slabB = slabA + 4096;

    const int fr = lane & 15;
    const int fkc = lane >> 4;     // 0..3
    const int rx = fr & 7;
    const int l3 = lane >> 3;      // 0..7
    const int gch = (lane & 7) ^ l3;   // swizzled global k-chunk for staging

    floatx4 acc[4][4];
    #pragma unroll
    for (int i = 0; i < 4; i++)
        #pragma unroll
        for (int j = 0; j < 4; j++) acc[i][j] = (floatx4)0.f;

    for (int kk = 0; kk < 512; kk += 64) {
        const int k0 = kbase + kk;
        // drain own ds_reads before overwriting slab (lgkmcnt(0), vmcnt don't-care)
        __builtin_amdgcn_s_waitcnt(0xC07F);
        #pragma unroll
        for (int j = 0; j < 8; j++) {
            int row = j * 8 + l3;
            const short* gpA = hidden + (size_t)(bm0 + row) * HID + k0 + gch * 8;
            __builtin_amdgcn_global_load_lds(
                (const __attribute__((address_space(1))) void*)gpA,
                (__attribute__((address_space(3))) void*)&slabA[j * 512 + lane * 8], 16, 0, 0);
            const short* gpB = Bt + (size_t)(bn0 + row) * HID + k0 + gch * 8;
            __builtin_amdgcn_global_load_lds(
                (const __attribute__((address_space(1))) void*)gpB,
                (__attribute__((address_space(3))) void*)&slabB[j * 512 + lane * 8], 16, 0, 0);
        }
        __builtin_amdgcn_sched_barrier(0);
        __builtin_amdgcn_s_waitcnt(0x0F70);   // vmcnt(0) only, per-wave
        __builtin_amdgcn_sched_barrier(0);
        #pragma unroll
        for (int s = 0; s < 2; s++) {
            const int slot = ((s * 4 + fkc) ^ rx) * 8;
            short8 af[4], bfr[4];
            #pragma unroll
            for (int mt = 0; mt < 4; mt++)
                af[mt] = *(const short8*)&slabA[(mt * 16 + fr) * 64 + slot];
            #pragma unroll
            for (int nt = 0; nt < 4; nt++)
                bfr[nt] = *(const short8*)&slabB[(nt * 16 + fr) * 64 + slot];
            #pragma unroll
            for (int mt = 0; mt < 4; mt++)
                #pragma unroll
                for (int nt = 0; nt < 4; nt++)
                    acc[mt][nt] = __builtin_amdgcn_mfma_f32_16x16x32_bf16(af[mt], bfr[nt], acc[mt][nt], 0, 0, 0);
        }
        __builtin_amdgcn_sched_barrier(0);
    }

    // write partial acc (fp32 [64][64]) into own slab, then reduce across 4 waves
    float* fslab = (float*)slabA;
    #pragma unroll
    for (int mt = 0; mt < 4; mt++)
        #pragma unroll
        for (int nt = 0; nt < 4; nt++)
            #pragma unroll
            for (int r = 0; r < 4; r++) {
                int row = mt * 16 + fkc * 4 + r;
                int col = nt * 16 + fr;
                fslab[row * 64 + col] = acc[mt][nt][r];
            }
    __syncthreads();

    const int rrow = tid >> 2;
    const int cb = (tid & 3) * 16;
    float4 v[4];
    #pragma unroll
    for (int ch = 0; ch < 4; ch++) v[ch] = make_float4(0.f, 0.f, 0.f, 0.f);
    #pragma unroll
    for (int w = 0; w < 4; w++) {
        const float* fs = (const float*)&lds[w * 8192];
        #pragma unroll
        for (int ch = 0; ch < 4; ch++) {
            float4 p = *(const float4*)&fs[rrow * 64 + cb + ch * 4];
            v[ch].x += p.x; v[ch].y += p.y; v[ch].z += p.z; v[ch].w += p.w;
        }
    }

    const float h = (t1p[0] - t0p[0]) / (float)NSTEPS;
    const float ah = alpha_c * h;
    const float h6 = h / 6.0f;
    const size_t base = (size_t)(bm0 + rrow) * DIM + bn0 + cb;
    #pragma unroll
    for (int ch = 0; ch < 4; ch++) {
        float4 bb = *(const float4*)&b2[bn0 + cb + ch * 4];
        float kv[4] = { v[ch].x + bb.x, v[ch].y + bb.y, v[ch].z + bb.z, v[ch].w + bb.w };
        size_t idx = base + ch * 4;
        float4 zv = *(const float4*)&z[idx];
        float zn[4];
        if (mode == 0) {
            *(float4*)&kacc[idx] = make_float4(kv[0], kv[1], kv[2], kv[3]);
            zn[0] = zv.x + ah * kv[0]; zn[1] = zv.y + ah * kv[1];
            zn[2] = zv.z + ah * kv[2]; zn[3] = zv.w + ah * kv[3];
        } else if (mode == 1) {
            float4 ka = *(const float4*)&kacc[idx];
            *(float4*)&kacc[idx] = make_float4(ka.x + wk * kv[0], ka.y + wk * kv[1],
                                               ka.z + wk * kv[2], ka.w + wk * kv[3]);
            zn[0] = zv.x + ah * kv[0]; zn[1] = zv.y + ah * kv[1];
            zn[2] = zv.z + ah * kv[2]; zn[3] = zv.w + ah * kv[3];
        } else {
            float4 ka = *(const float4*)&kacc[idx];
            zn[0] = zv.x + h6 * (ka.x + kv[0]); zn[1] = zv.y + h6 * (ka.y + kv[1]);
            zn[2] = zv.z + h6 * (ka.z + kv[2]); zn[3] = zv.w + h6 * (ka.w + kv[3]);
            *(float4*)&z[idx] = make_float4(zn[0], zn[1], zn[2], zn[3]);
        }
        short4v o;
        o[0] = f2bf(zn[0]); o[1] = f2bf(zn[1]); o[2] = f2bf(zn[2]); o[3] = f2bf(zn[3]);
        *(short4v*)&abuf[idx] = o;
    }
}

extern "C" void kernel_launch(void* const* d_in, const int* in_sizes, int n_in,
                              void* d_out, int out_size, void* d_ws, size_t ws_size,
                              hipStream_t stream) {
    const float* z0  = (const float*)d_in[0];
    const float* W1  = (const float*)d_in[1];
    const float* b1  = (const float*)d_in[2];
    const float* W2  = (const float*)d_in[3];
    const float* b2  = (const float*)d_in[4];
    const float* t0p = (const float*)d_in[5];
    const float* t1p = (const float*)d_in[6];
    float* z = (float*)d_out;

    char* ws = (char*)d_ws;
    short* W1t    = (short*)(ws);                              // 2 MB
    short* W2t    = (short*)(ws + (2u << 20));                 // 2 MB
    float* w1last = (float*)(ws + (4u << 20));                 // 8 KB (pad 64 KB)
    short* abuf   = (short*)(ws + (4u << 20) + (1u << 16));    // 4 MB
    short* hidden = (short*)(ws + (8u << 20) + (1u << 16));    // 16 MB
    float* kacc   = (float*)(ws + (24u << 20) + (1u << 16));   // 8 MB

    hipMemcpyAsync(z, z0, (size_t)BATCH * DIM * sizeof(float),
                   hipMemcpyDeviceToDevice, stream);
    transpose_cvt<<<dim3(DIM / 32, HID / 32), dim3(32, 8), 0, stream>>>(W1, W1t, DIM, HID);
    transpose_cvt<<<dim3(HID / 32, DIM / 32), dim3(32, 8), 0, stream>>>(W2, W2t, HID, DIM);
    extract_row<<<HID / 256, 256, 0, stream>>>(W1, w1last);
    init_abuf<<<BATCH * DIM / 4 / 256, 256, 0, stream>>>(z0, abuf);

    const dim3 g1(BATCH / 128, HID / 128), g2(BATCH / 64, DIM / 64), b(256);
    for (int i = 0; i < NSTEPS; i++) {
        float fi = (float)i;
        // k1 -> abuf for k2
        gemm1_tanh<<<g1, b, 0, stream>>>(abuf, W1t, b1, w1last, t0p, t1p, 0.0f, fi, hidden);
        gemm2_fused<<<g2, b, 0, stream>>>(hidden, W2t, b2, z, kacc, abuf, t0p, t1p, 0, 1.0f, 0.5f);
        // k2 -> abuf for k3
        gemm1_tanh<<<g1, b, 0, stream>>>(abuf, W1t, b1, w1last, t0p, t1p, 0.5f, fi, hidden);
        gemm2_fused<<<g2, b, 0, stream>>>(hidden, W2t, b2, z, kacc, abuf, t0p, t1p, 1, 2.0f, 0.5f);
        // k3 -> abuf for k4
        gemm1_tanh<<<g1, b, 0, stream>>>(abuf, W1t, b1, w1last, t0p, t1p, 0.5f, fi, hidden);
        gemm2_fused<<<g2, b, 0, stream>>>(hidden, W2t, b2, z, kacc, abuf, t0p, t1p, 1, 2.0f, 1.0f);
        // k4: z += (h/6)*(kacc + k4) ; abuf = bf16(z_new)
        gemm1_tanh<<<g1, b, 0, stream>>>(abuf, W1t, b1, w1last, t0p, t1p, 1.0f, fi, hidden);
        gemm2_fused<<<g2, b, 0, stream>>>(hidden, W2t, b2, z, kacc, abuf, t0p, t1p, 2, 1.0f, 0.0f);
    }
}